// Round 1
// baseline (282.421 us; speedup 1.0000x reference)
//
#include <hip/hip_runtime.h>

#define NTOK  16384   // B*T
#define KDIM  512
#define NQKV  1536
#define NB    4
#define TT    4096

using frag8   = __attribute__((ext_vector_type(8))) short;
using floatx4 = __attribute__((ext_vector_type(4))) float;

__device__ __forceinline__ unsigned short f2b(float f) {
  union { float f; unsigned u; } v; v.f = f;
  unsigned r = v.u + 0x7fffu + ((v.u >> 16) & 1u);
  return (unsigned short)(r >> 16);
}
__device__ __forceinline__ float b2f(unsigned short s) {
  union { unsigned u; float f; } v; v.u = ((unsigned)s) << 16; return v.f;
}
__device__ __forceinline__ float blo(unsigned w) {
  union { unsigned u; float f; } v; v.u = w << 16; return v.f;
}
__device__ __forceinline__ float bhi(unsigned w) {
  union { unsigned u; float f; } v; v.u = w & 0xffff0000u; return v.f;
}

__device__ __forceinline__ void gl_lds16(const void* g, void* l) {
  __builtin_amdgcn_global_load_lds((__attribute__((address_space(1))) const void*)g,
                                   (__attribute__((address_space(3))) void*)l,
                                   16, 0, 0);
}

// ---------------- convert kernels ----------------
__global__ __launch_bounds__(256) void cvt_x(const float* __restrict__ x,
                                             unsigned short* __restrict__ xb) {
  const size_t i = (size_t)blockIdx.x * 256 + threadIdx.x;   // one float4 per thread
  const float4 v = ((const float4*)x)[i];
  ushort4 o;
  o.x = f2b(v.x); o.y = f2b(v.y); o.z = f2b(v.z); o.w = f2b(v.w);
  ((ushort4*)xb)[i] = o;
}

__global__ __launch_bounds__(256) void prep_weights(
    const float* __restrict__ Wq, const float* __restrict__ Wk,
    const float* __restrict__ Wv, const float* __restrict__ Wp,
    const float* __restrict__ bq, const float* __restrict__ bk,
    const float* __restrict__ bv,
    unsigned short* __restrict__ wqkv, unsigned short* __restrict__ wp,
    float* __restrict__ bias_qkv) {
  const int idx = blockIdx.x * 256 + threadIdx.x;
  if (idx < 786432) {                       // 1536*512
    const int m = idx >> 9, i = idx & 511;
    const float* W = (m < 512) ? Wq : ((m < 1024) ? Wk : Wv);
    wqkv[idx] = f2b(W[(m & 511) * 512 + i]);
    return;
  }
  const int j = idx - 786432;
  if (j < 262144) { wp[j] = f2b(Wp[j]); return; }
  const int c = j - 262144;
  if (c < 1536)
    bias_qkv[c] = (c < 512) ? bq[c] : ((c < 1024) ? bk[c - 512] : bv[c - 1024]);
}

// ---------------- m97-style bf16 GEMM, B^T input ----------------
// C[M][ldc] = A[M][K] @ B[N][K]^T + bias[N];  M%128==0, N%128==0, K%32==0
template<int STORE_BF16>
__global__ __launch_bounds__(256, 2) void gemm_bt(
    const unsigned short* __restrict__ A,
    const unsigned short* __restrict__ Bm,
    const float* __restrict__ bias,
    void* __restrict__ C,
    int M, int N, int K, int ldc)
{
  __shared__ unsigned short As[128 * 32];
  __shared__ unsigned short Bs[128 * 32];
  const int tid  = threadIdx.x;
  const int wave = tid >> 6;
  const int lane = tid & 63;
  const int quad = lane >> 4;
  const int lr   = lane & 15;
  const int nt   = N >> 7;
  const int bn   = (blockIdx.x % nt) << 7;
  const int bm   = (blockIdx.x / nt) << 7;
  const int wm   = (wave >> 1) << 6;
  const int wn   = (wave & 1) << 6;

  floatx4 acc[4][4] = {};

  // staging: thread -> (row = tid/4, 16B chunk = tid%4)
  const int srow = tid >> 2;
  const int scol = (tid & 3) << 3;
  const unsigned short* Ag = A + (size_t)(bm + srow) * K + scol;
  const unsigned short* Bg = Bm + (size_t)(bn + srow) * K + scol;
  unsigned short* Al = As + (wave << 9);   // wave-uniform LDS base, HW adds lane*16B
  unsigned short* Bl = Bs + (wave << 9);

  for (int k0 = 0; k0 < K; k0 += 32) {
    __syncthreads();
    gl_lds16(Ag + k0, Al);
    gl_lds16(Ag + (size_t)64 * K + k0, Al + 64 * 32);
    gl_lds16(Bg + k0, Bl);
    gl_lds16(Bg + (size_t)64 * K + k0, Bl + 64 * 32);
    __syncthreads();

    frag8 af[4], bf[4];
#pragma unroll
    for (int i = 0; i < 4; i++)
      af[i] = *(const frag8*)&As[(wm + (i << 4) + lr) * 32 + (quad << 3)];
#pragma unroll
    for (int j = 0; j < 4; j++)
      bf[j] = *(const frag8*)&Bs[(wn + (j << 4) + lr) * 32 + (quad << 3)];
#pragma unroll
    for (int i = 0; i < 4; i++)
#pragma unroll
      for (int j = 0; j < 4; j++)
        acc[i][j] = __builtin_amdgcn_mfma_f32_16x16x32_bf16(af[i], bf[j], acc[i][j], 0, 0, 0);
  }

  // epilogue: C/D layout col=lane&15, row=quad*4+reg
  const int crow0 = bm + wm + (quad << 2);
  const int ccol0 = bn + wn + lr;
#pragma unroll
  for (int j = 0; j < 4; j++) {
    const int col = ccol0 + (j << 4);
    const float bv = bias[col];
#pragma unroll
    for (int i = 0; i < 4; i++) {
      const int row = crow0 + (i << 4);
#pragma unroll
      for (int r = 0; r < 4; r++) {
        const float v = acc[i][j][r] + bv;
        if (STORE_BF16)
          ((unsigned short*)C)[(size_t)(row + r) * ldc + col] = f2b(v);
        else
          ((float*)C)[(size_t)(row + r) * ldc + col] = v;
      }
    }
  }
}

// ---------------- per-head softmax over 64 dims of q,k (in place) ----------------
__global__ __launch_bounds__(256) void softmax_qk(unsigned short* __restrict__ qkv) {
  const int gw   = (blockIdx.x << 2) + (threadIdx.x >> 6);  // global wave id
  const int lane = threadIdx.x & 63;
  const int tok  = gw >> 4;
  const int r    = gw & 15;            // 16 rows of 64 = q(8 heads) + k(8 heads)
  unsigned short* p = qkv + (size_t)tok * NQKV + (r << 6) + lane;
  const float x = b2f(*p);
  float m = x;
#pragma unroll
  for (int off = 32; off; off >>= 1) m = fmaxf(m, __shfl_xor(m, off));
  const float e = __expf(x - m);
  float s = e;
#pragma unroll
  for (int off = 32; off; off >>= 1) s += __shfl_xor(s, off);
  *p = f2b(e / s);
}

// ---------------- k_sum[b][c] = sum_t k ----------------
__global__ __launch_bounds__(256) void ksum_reduce(const unsigned short* __restrict__ qkv,
                                                   float* __restrict__ ksum) {
  const int b  = blockIdx.x >> 5;      // 4 batches x 32 t-chunks
  const int tc = blockIdx.x & 31;
  const int c  = threadIdx.x;          // cols c, c+256 of the 512 k-cols
  float s0 = 0.f, s1 = 0.f;
  const int t0 = b * TT + tc * 128;
  for (int t = 0; t < 128; t++) {
    const unsigned short* row = qkv + (size_t)(t0 + t) * NQKV + 512;
    s0 += b2f(row[c]);
    s1 += b2f(row[c + 256]);
  }
  atomicAdd(&ksum[b * 512 + c], s0);
  atomicAdd(&ksum[b * 512 + c + 256], s1);
}

// ---------------- context[bh][d][e] = sum_t k[t][d] v[t][e] ----------------
__global__ __launch_bounds__(256) void kv_context(const unsigned short* __restrict__ qkv,
                                                  float* __restrict__ ctx) {
  const int bid = blockIdx.x;          // 32 bh x 16 t-chunks
  const int tc  = bid & 15;
  const int bh  = bid >> 4;
  const int b   = bh >> 3, h = bh & 7;
  __shared__ float ks[16 * 64];
  __shared__ float vs[16 * 64];
  const int tid = threadIdx.x;
  const int ty = tid >> 4, tx = tid & 15;
  floatx4 acc[4] = {};

  const int si    = tid << 3;          // element 0..2047 of a 16-row stage
  const int strow = si >> 7;
  const int sw    = si & 127;
  const int t0    = b * TT + tc * 256;
  const unsigned short* gcol = qkv + ((sw < 64) ? (512 + h * 64 + sw)
                                                : (1024 + h * 64 + (sw - 64)));
  float* sdst = (sw < 64) ? &ks[strow * 64 + sw] : &vs[strow * 64 + (sw - 64)];

  for (int tt = 0; tt < 256; tt += 16) {
    __syncthreads();
    const uint4 raw = *(const uint4*)(gcol + (size_t)(t0 + tt + strow) * NQKV);
    sdst[0] = blo(raw.x); sdst[1] = bhi(raw.x);
    sdst[2] = blo(raw.y); sdst[3] = bhi(raw.y);
    sdst[4] = blo(raw.z); sdst[5] = bhi(raw.z);
    sdst[6] = blo(raw.w); sdst[7] = bhi(raw.w);
    __syncthreads();
#pragma unroll
    for (int t = 0; t < 16; t++) {
      const floatx4 kv = *(const floatx4*)&ks[t * 64 + (ty << 2)];
      const floatx4 vv = *(const floatx4*)&vs[t * 64 + (tx << 2)];
      acc[0] += kv.x * vv;
      acc[1] += kv.y * vv;
      acc[2] += kv.z * vv;
      acc[3] += kv.w * vv;
    }
  }
  float* cg = ctx + (size_t)bh * 4096 + (ty << 2) * 64 + (tx << 2);
#pragma unroll
  for (int i = 0; i < 4; i++)
#pragma unroll
    for (int j = 0; j < 4; j++)
      atomicAdd(&cg[i * 64 + j], acc[i][j]);
}

// ---------------- out_pre = q @ ctx * D_inv + q  (bf16) ----------------
__global__ __launch_bounds__(256) void attn_out(const unsigned short* __restrict__ qkv,
                                                const float* __restrict__ ctx,
                                                const float* __restrict__ ksum,
                                                unsigned short* __restrict__ opre) {
  const int bid = blockIdx.x;          // 4b x 8h x 64 t-chunks = 2048
  const int tchunk = bid & 63;
  const int h = (bid >> 6) & 7;
  const int b = bid >> 9;
  __shared__ float cs[64 * 64];
  __shared__ float qs[64 * 65];        // +1 pad: kills 16-way bank conflict on qrow[d]
  __shared__ float kss[64];
  const int tid = threadIdx.x;

  const float* cg = ctx + ((size_t)(b * 8 + h) << 12);
  for (int i = tid; i < 1024; i += 256)
    *(floatx4*)&cs[i << 2] = *(const floatx4*)&cg[i << 2];
  if (tid < 64) kss[tid] = ksum[b * 512 + h * 64 + tid];
  const int t0 = b * TT + (tchunk << 6);
  for (int i = tid; i < 512; i += 256) {
    const int tok = i >> 3, c8 = (i & 7) << 3;
    const uint4 raw = *(const uint4*)&qkv[(size_t)(t0 + tok) * NQKV + h * 64 + c8];
    float* d = &qs[tok * 65 + c8];
    d[0] = blo(raw.x); d[1] = bhi(raw.x);
    d[2] = blo(raw.y); d[3] = bhi(raw.y);
    d[4] = blo(raw.z); d[5] = bhi(raw.z);
    d[6] = blo(raw.w); d[7] = bhi(raw.w);
  }
  __syncthreads();

  const int tok = tid >> 2, e0 = (tid & 3) << 4;
  floatx4 o[4] = {};
  float dsum = 0.f;
  const float* qrow = qs + tok * 65;
  for (int d = 0; d < 64; d++) {
    const float qd = qrow[d];
    dsum += qd * kss[d];
    const floatx4* cr = (const floatx4*)&cs[d * 64 + e0];
    o[0] += qd * cr[0];
    o[1] += qd * cr[1];
    o[2] += qd * cr[2];
    o[3] += qd * cr[3];
  }
  const float dinv = 1.f / dsum;
  unsigned short* orow = opre + (size_t)(t0 + tok) * 512 + h * 64 + e0;
#pragma unroll
  for (int v = 0; v < 4; v++)
#pragma unroll
    for (int r = 0; r < 4; r++)
      orow[(v << 2) + r] = f2b(o[v][r] * dinv + qrow[e0 + (v << 2) + r]);
}

// ---------------- launch ----------------
extern "C" void kernel_launch(void* const* d_in, const int* in_sizes, int n_in,
                              void* d_out, int out_size, void* d_ws, size_t ws_size,
                              hipStream_t stream) {
  (void)in_sizes; (void)n_in; (void)out_size; (void)ws_size;
  const float* x  = (const float*)d_in[0];
  const float* Wq = (const float*)d_in[1];
  const float* bq = (const float*)d_in[2];
  const float* Wk = (const float*)d_in[3];
  const float* bk = (const float*)d_in[4];
  const float* Wv = (const float*)d_in[5];
  const float* bv = (const float*)d_in[6];
  const float* Wp = (const float*)d_in[7];
  const float* bp = (const float*)d_in[8];

  char* w = (char*)d_ws;
  unsigned short* xb   = (unsigned short*)w; w += (size_t)NTOK * KDIM * 2;   // 16 MB
  unsigned short* wqkv = (unsigned short*)w; w += (size_t)NQKV * KDIM * 2;   // 1.5 MB
  unsigned short* wp   = (unsigned short*)w; w += (size_t)KDIM * KDIM * 2;   // 0.5 MB
  float* bias_qkv      = (float*)w;          w += (size_t)NQKV * 4;          // 6 KB
  float* ksum          = (float*)w;          w += (size_t)NB * KDIM * 4;     // 8 KB
  float* ctx           = (float*)w;          w += (size_t)32 * 64 * 64 * 4;  // 512 KB
  unsigned short* qkv  = (unsigned short*)w; w += (size_t)NTOK * NQKV * 2;   // 48 MB
  unsigned short* opre = (unsigned short*)w; w += (size_t)NTOK * KDIM * 2;   // 16 MB

  // zero ksum + ctx (adjacent)
  hipMemsetAsync(ksum, 0, (size_t)NB * KDIM * 4 + (size_t)32 * 64 * 64 * 4, stream);

  cvt_x<<<8192, 256, 0, stream>>>(x, xb);
  prep_weights<<<4102, 256, 0, stream>>>(Wq, Wk, Wv, Wp, bq, bk, bv, wqkv, wp, bias_qkv);
  gemm_bt<1><<<(NTOK / 128) * (NQKV / 128), 256, 0, stream>>>(
      xb, wqkv, bias_qkv, qkv, NTOK, NQKV, KDIM, NQKV);
  softmax_qk<<<65536, 256, 0, stream>>>(qkv);
  ksum_reduce<<<128, 256, 0, stream>>>(qkv, ksum);
  kv_context<<<512, 256, 0, stream>>>(qkv, ctx);
  attn_out<<<2048, 256, 0, stream>>>(qkv, ctx, ksum, opre);
  gemm_bt<0><<<(NTOK / 128) * (KDIM / 128), 256, 0, stream>>>(
      opre, wp, bp, d_out, NTOK, KDIM, KDIM, KDIM);
}

// Round 2
// 235.884 us; speedup vs baseline: 1.1973x; 1.1973x over previous
//
#include <hip/hip_runtime.h>

#define NTOK  16384   // B*T
#define KDIM  512
#define NQKV  1536
#define TT    4096

using frag8   = __attribute__((ext_vector_type(8))) short;
using floatx4 = __attribute__((ext_vector_type(4))) float;

__device__ __forceinline__ unsigned short f2b(float f) {
  union { float f; unsigned u; } v; v.f = f;
  unsigned r = v.u + 0x7fffu + ((v.u >> 16) & 1u);
  return (unsigned short)(r >> 16);
}
__device__ __forceinline__ float b2f(unsigned short s) {
  union { unsigned u; float f; } v; v.u = ((unsigned)s) << 16; return v.f;
}
__device__ __forceinline__ float blo(unsigned w) {
  union { unsigned u; float f; } v; v.u = w << 16; return v.f;
}
__device__ __forceinline__ float bhi(unsigned w) {
  union { unsigned u; float f; } v; v.u = w & 0xffff0000u; return v.f;
}

__device__ __forceinline__ void gl_lds16(const void* g, void* l) {
  __builtin_amdgcn_global_load_lds((__attribute__((address_space(1))) const void*)g,
                                   (__attribute__((address_space(3))) void*)l,
                                   16, 0, 0);
}

// ---------------- convert kernels ----------------
__global__ __launch_bounds__(256) void cvt_x(const float* __restrict__ x,
                                             unsigned short* __restrict__ xb) {
  const size_t i = (size_t)blockIdx.x * 256 + threadIdx.x;
  const float4 v = ((const float4*)x)[i];
  ushort4 o;
  o.x = f2b(v.x); o.y = f2b(v.y); o.z = f2b(v.z); o.w = f2b(v.w);
  ((ushort4*)xb)[i] = o;
}

__global__ __launch_bounds__(256) void prep_weights(
    const float* __restrict__ Wq, const float* __restrict__ Wk,
    const float* __restrict__ Wv, const float* __restrict__ Wp,
    const float* __restrict__ bq, const float* __restrict__ bk,
    const float* __restrict__ bv,
    unsigned short* __restrict__ wqkv, unsigned short* __restrict__ wp,
    float* __restrict__ bias_qkv) {
  const int idx = blockIdx.x * 256 + threadIdx.x;
  if (idx < 786432) {                       // 1536*512
    const int m = idx >> 9, i = idx & 511;
    const float* W = (m < 512) ? Wq : ((m < 1024) ? Wk : Wv);
    wqkv[idx] = f2b(W[(m & 511) * 512 + i]);
    return;
  }
  const int j = idx - 786432;
  if (j < 262144) { wp[j] = f2b(Wp[j]); return; }
  const int c = j - 262144;
  if (c < 1536)
    bias_qkv[c] = (c < 512) ? bq[c] : ((c < 1024) ? bk[c - 512] : bv[c - 1024]);
}

// ---------------- m97-style bf16 GEMM, B^T input ----------------
// SOFT=1: qkv GEMM — fused per-head softmax on q/k regions + ksum atomics, bf16 store.
// SOFT=0: plain fp32 store + bias.
template<int SOFT>
__global__ __launch_bounds__(256, 2) void gemm_bt(
    const unsigned short* __restrict__ A,
    const unsigned short* __restrict__ Bm,
    const float* __restrict__ bias,
    void* __restrict__ C,
    float* __restrict__ ksum,
    int M, int N, int K, int ldc)
{
  __shared__ unsigned short As[128 * 32];
  __shared__ unsigned short Bs[128 * 32];
  const int tid  = threadIdx.x;
  const int wave = tid >> 6;
  const int lane = tid & 63;
  const int quad = lane >> 4;
  const int lr   = lane & 15;
  const int nt   = N >> 7;
  const int bn   = (blockIdx.x % nt) << 7;
  const int bm   = (blockIdx.x / nt) << 7;
  const int wm   = (wave >> 1) << 6;
  const int wn   = (wave & 1) << 6;

  floatx4 acc[4][4] = {};

  const int srow = tid >> 2;
  const int scol = (tid & 3) << 3;
  const unsigned short* Ag = A + (size_t)(bm + srow) * K + scol;
  const unsigned short* Bg = Bm + (size_t)(bn + srow) * K + scol;
  unsigned short* Al = As + (wave << 9);
  unsigned short* Bl = Bs + (wave << 9);

  for (int k0 = 0; k0 < K; k0 += 32) {
    __syncthreads();
    gl_lds16(Ag + k0, Al);
    gl_lds16(Ag + (size_t)64 * K + k0, Al + 64 * 32);
    gl_lds16(Bg + k0, Bl);
    gl_lds16(Bg + (size_t)64 * K + k0, Bl + 64 * 32);
    __syncthreads();

    frag8 af[4], bf[4];
#pragma unroll
    for (int i = 0; i < 4; i++)
      af[i] = *(const frag8*)&As[(wm + (i << 4) + lr) * 32 + (quad << 3)];
#pragma unroll
    for (int j = 0; j < 4; j++)
      bf[j] = *(const frag8*)&Bs[(wn + (j << 4) + lr) * 32 + (quad << 3)];
#pragma unroll
    for (int i = 0; i < 4; i++)
#pragma unroll
      for (int j = 0; j < 4; j++)
        acc[i][j] = __builtin_amdgcn_mfma_f32_16x16x32_bf16(af[i], bf[j], acc[i][j], 0, 0, 0);
  }

  // epilogue: C/D layout col=lane&15, row=quad*4+reg
  const int crow0 = bm + wm + (quad << 2);
  const int ccol0 = bn + wn + lr;

  // bias into acc
#pragma unroll
  for (int j = 0; j < 4; j++) {
    const float bv = bias[ccol0 + (j << 4)];
#pragma unroll
    for (int i = 0; i < 4; i++)
#pragma unroll
      for (int r = 0; r < 4; r++)
        acc[i][j][r] += bv;
  }

  if (SOFT) {
    const int region = (bn + wn) >> 9;   // 0=q, 1=k, 2=v (wave-uniform)
    if (region < 2) {
      float ksa[4] = {0.f, 0.f, 0.f, 0.f};
#pragma unroll
      for (int i = 0; i < 4; i++)
#pragma unroll
        for (int r = 0; r < 4; r++) {
          // softmax over the 64 head-dims: 4 j-vals/lane x 16 lanes (same quad)
          float e0 = __expf(acc[i][0][r]);
          float e1 = __expf(acc[i][1][r]);
          float e2 = __expf(acc[i][2][r]);
          float e3 = __expf(acc[i][3][r]);
          float s = e0 + e1 + e2 + e3;
          s += __shfl_xor(s, 1);
          s += __shfl_xor(s, 2);
          s += __shfl_xor(s, 4);
          s += __shfl_xor(s, 8);
          const float inv = 1.f / s;
          e0 *= inv; e1 *= inv; e2 *= inv; e3 *= inv;
          acc[i][0][r] = e0; acc[i][1][r] = e1;
          acc[i][2][r] = e2; acc[i][3][r] = e3;
          ksa[0] += e0; ksa[1] += e1; ksa[2] += e2; ksa[3] += e3;
        }
      if (region == 1) {
        const int b = bm >> 12;
#pragma unroll
        for (int j = 0; j < 4; j++)
          atomicAdd(&ksum[b * 512 + ccol0 + (j << 4) - 512], ksa[j]);
      }
    }
  }

#pragma unroll
  for (int j = 0; j < 4; j++) {
    const int col = ccol0 + (j << 4);
#pragma unroll
    for (int i = 0; i < 4; i++) {
      const int row = crow0 + (i << 4);
#pragma unroll
      for (int r = 0; r < 4; r++) {
        const float v = acc[i][j][r];
        if (SOFT)
          ((unsigned short*)C)[(size_t)(row + r) * ldc + col] = f2b(v);
        else
          ((float*)C)[(size_t)(row + r) * ldc + col] = v;
      }
    }
  }
}

// ---------------- partial ctxT[e][d] per (chunk,bh) ----------------
// part[(tc*32+bh)][e][d] = sum over 128 tokens of v[t][e]*k'[t][d]
__global__ __launch_bounds__(256) void kv_context(const unsigned short* __restrict__ qkv,
                                                  float* __restrict__ part) {
  const int bid = blockIdx.x;          // 32 bh x 32 t-chunks
  const int tc  = bid & 31;
  const int bh  = bid >> 5;
  const int b   = bh >> 3, h = bh & 7;
  __shared__ float ks[16 * 64];
  __shared__ float vs[16 * 64];
  const int tid = threadIdx.x;
  const int ty = tid >> 4, tx = tid & 15;
  floatx4 acc[4] = {};

  const int si    = tid << 3;
  const int strow = si >> 7;
  const int sw    = si & 127;
  const int t0    = b * TT + tc * 128;
  const unsigned short* gcol = qkv + ((sw < 64) ? (512 + h * 64 + sw)
                                                : (1024 + h * 64 + (sw - 64)));
  float* sdst = (sw < 64) ? &ks[strow * 64 + sw] : &vs[strow * 64 + (sw - 64)];

  for (int tt = 0; tt < 128; tt += 16) {
    __syncthreads();
    const uint4 raw = *(const uint4*)(gcol + (size_t)(t0 + tt + strow) * NQKV);
    sdst[0] = blo(raw.x); sdst[1] = bhi(raw.x);
    sdst[2] = blo(raw.y); sdst[3] = bhi(raw.y);
    sdst[4] = blo(raw.z); sdst[5] = bhi(raw.z);
    sdst[6] = blo(raw.w); sdst[7] = bhi(raw.w);
    __syncthreads();
#pragma unroll
    for (int t = 0; t < 16; t++) {
      const floatx4 vb = *(const floatx4*)&vs[t * 64 + (ty << 2)];  // 4 e's (broadcast x16)
      const floatx4 kb = *(const floatx4*)&ks[t * 64 + (tx << 2)];  // 4 d's
      acc[0] += vb.x * kb;
      acc[1] += vb.y * kb;
      acc[2] += vb.z * kb;
      acc[3] += vb.w * kb;
    }
  }
  // acc[i][j] = ctxT[e=ty*4+i][d=tx*4+j]; coalesced float4 store
  float* pg = part + ((size_t)(tc * 32 + bh) << 12) + (size_t)(ty << 2) * 64 + (tx << 2);
#pragma unroll
  for (int i = 0; i < 4; i++)
    *(floatx4*)(pg + i * 64) = acc[i];
}

// ---------------- reduce partials -> ctxb bf16 [bh][80][64] ----------------
// rows 0-63 = ctxT, row 64 = ksum, rows 65-79 = 0
__global__ __launch_bounds__(256) void ctx_reduce(const float* __restrict__ part,
                                                  const float* __restrict__ ksum,
                                                  unsigned short* __restrict__ ctxb) {
  const int bh = blockIdx.x / 5, g = blockIdx.x % 5;
  const int tid = threadIdx.x;
  const int row = g * 16 + (tid >> 4);
  const int d0  = (tid & 15) << 2;
  floatx4 s = {0.f, 0.f, 0.f, 0.f};
  if (row < 64) {
    const float* p = part + ((size_t)bh << 12) + row * 64 + d0;
    for (int c = 0; c < 32; c++)
      s += *(const floatx4*)(p + ((size_t)(c * 32) << 12));
  } else if (row == 64) {
    const int b = bh >> 3, h = bh & 7;
    s = *(const floatx4*)&ksum[b * 512 + h * 64 + d0];
  }
  ushort4 o;
  o.x = f2b(s.x); o.y = f2b(s.y); o.z = f2b(s.z); o.w = f2b(s.w);
  *(ushort4*)&ctxb[(size_t)bh * 5120 + (row << 6) + d0] = o;
}

// ---------------- attn_out via MFMA: outT[e][t] = ctxT[e][:]·q'[t][:] ----------------
__global__ __launch_bounds__(256) void attn_out(const unsigned short* __restrict__ qkv,
                                                const unsigned short* __restrict__ ctxb,
                                                unsigned short* __restrict__ opre) {
  const int bid = blockIdx.x;          // bh(32) x tchunk(64)
  const int tc = bid & 63;
  const int bh = bid >> 6;
  const int b = bh >> 3, h = bh & 7;
  const int t0 = b * TT + (tc << 6);
  __shared__ unsigned short sh[144 * 72];   // qs[64][72] | cs[80][72] (cs reused as os)
  unsigned short* qs = sh;
  unsigned short* cs = sh + 64 * 72;
  unsigned short* os = cs;
  const int tid = threadIdx.x;

  for (int i = tid; i < 512; i += 256) {
    const int row = i >> 3, c8 = (i & 7) << 3;
    *(uint4*)&qs[row * 72 + c8] =
        *(const uint4*)&qkv[(size_t)(t0 + row) * NQKV + h * 64 + c8];
  }
  for (int i = tid; i < 640; i += 256) {
    const int row = i >> 3, c8 = (i & 7) << 3;
    *(uint4*)&cs[row * 72 + c8] =
        *(const uint4*)&ctxb[(size_t)bh * 5120 + (row << 6) + c8];
  }
  __syncthreads();

  const int lane = tid & 63, w = tid >> 6, quad = lane >> 4, lr = lane & 15;
  floatx4 acc[5] = {};
#pragma unroll
  for (int k2 = 0; k2 < 2; k2++) {
    const int d0 = (k2 << 5) + (quad << 3);
    const frag8 bf = *(const frag8*)&qs[((w << 4) + lr) * 72 + d0];
#pragma unroll
    for (int et = 0; et < 5; et++) {
      const frag8 af = *(const frag8*)&cs[(et * 16 + lr) * 72 + d0];
      acc[et] = __builtin_amdgcn_mfma_f32_16x16x32_bf16(af, bf, acc[et], 0, 0, 0);
    }
  }
  // C[e][t]: col=lane&15 -> t (within wave's 16 tokens), row=quad*4+r.
  // dsum[t] = C[64][t] lives in quad-0 lanes, reg 0 of tile 4.
  const float dinv = 1.f / __shfl(acc[4][0], lr);
  __syncthreads();                      // done reading cs; reuse as os

  const int trow = (w << 4) + lr;
#pragma unroll
  for (int et = 0; et < 4; et++)
#pragma unroll
    for (int r = 0; r < 4; r++) {
      const int e = et * 16 + (quad << 2) + r;
      const float qv = b2f(qs[trow * 72 + e]);
      os[trow * 72 + e] = f2b(acc[et][r] * dinv + qv);
    }
  __syncthreads();

  for (int i = tid; i < 512; i += 256) {
    const int row = i >> 3, c8 = (i & 7) << 3;
    *(uint4*)&opre[(size_t)(t0 + row) * KDIM + h * 64 + c8] = *(const uint4*)&os[row * 72 + c8];
  }
}

// ---------------- launch ----------------
extern "C" void kernel_launch(void* const* d_in, const int* in_sizes, int n_in,
                              void* d_out, int out_size, void* d_ws, size_t ws_size,
                              hipStream_t stream) {
  (void)in_sizes; (void)n_in; (void)out_size; (void)ws_size;
  const float* x  = (const float*)d_in[0];
  const float* Wq = (const float*)d_in[1];
  const float* bq = (const float*)d_in[2];
  const float* Wk = (const float*)d_in[3];
  const float* bk = (const float*)d_in[4];
  const float* Wv = (const float*)d_in[5];
  const float* bv = (const float*)d_in[6];
  const float* Wp = (const float*)d_in[7];
  const float* bp = (const float*)d_in[8];

  char* w = (char*)d_ws;
  unsigned short* xb   = (unsigned short*)w; w += (size_t)NTOK * KDIM * 2;   // 16 MB
  float* part          = (float*)xb;         // alias: xb dead after qkv GEMM; 32*32*4096*4 = 16 MB
  unsigned short* wqkv = (unsigned short*)w; w += (size_t)NQKV * KDIM * 2;   // 1.5 MB
  unsigned short* wp   = (unsigned short*)w; w += (size_t)KDIM * KDIM * 2;   // 0.5 MB
  float* bias_qkv      = (float*)w;          w += (size_t)NQKV * 4;          // 6 KB
  float* ksum          = (float*)w;          w += (size_t)4 * KDIM * 4;      // 8 KB
  unsigned short* ctxb = (unsigned short*)w; w += (size_t)32 * 80 * 64 * 2;  // 320 KB
  unsigned short* qkv  = (unsigned short*)w; w += (size_t)NTOK * NQKV * 2;   // 48 MB
  unsigned short* opre = (unsigned short*)w; w += (size_t)NTOK * KDIM * 2;   // 16 MB

  hipMemsetAsync(ksum, 0, (size_t)4 * KDIM * 4, stream);

  cvt_x<<<8192, 256, 0, stream>>>(x, xb);
  prep_weights<<<4102, 256, 0, stream>>>(Wq, Wk, Wv, Wp, bq, bk, bv, wqkv, wp, bias_qkv);
  gemm_bt<1><<<(NTOK / 128) * (NQKV / 128), 256, 0, stream>>>(
      xb, wqkv, bias_qkv, qkv, ksum, NTOK, NQKV, KDIM, NQKV);
  kv_context<<<1024, 256, 0, stream>>>(qkv, part);
  ctx_reduce<<<160, 256, 0, stream>>>(part, ksum, ctxb);
  attn_out<<<2048, 256, 0, stream>>>(qkv, ctxb, opre);
  gemm_bt<0><<<(NTOK / 128) * (KDIM / 128), 256, 0, stream>>>(
      opre, wp, bp, d_out, nullptr, NTOK, KDIM, KDIM, KDIM);
}

// Round 3
// 192.697 us; speedup vs baseline: 1.4656x; 1.2241x over previous
//
#include <hip/hip_runtime.h>

#define NTOK  16384   // B*T
#define KDIM  512
#define NQKV  1536
#define TT    4096

using frag8   = __attribute__((ext_vector_type(8))) short;
using floatx4 = __attribute__((ext_vector_type(4))) float;

__device__ __forceinline__ unsigned short f2b(float f) {
  union { float f; unsigned u; } v; v.f = f;
  unsigned r = v.u + 0x7fffu + ((v.u >> 16) & 1u);
  return (unsigned short)(r >> 16);
}
__device__ __forceinline__ float b2f(unsigned short s) {
  union { unsigned u; float f; } v; v.u = ((unsigned)s) << 16; return v.f;
}
__device__ __forceinline__ float blo(unsigned w) {
  union { unsigned u; float f; } v; v.u = w << 16; return v.f;
}
__device__ __forceinline__ float bhi(unsigned w) {
  union { unsigned u; float f; } v; v.u = w & 0xffff0000u; return v.f;
}

__device__ __forceinline__ void gl_lds16(const void* g, void* l) {
  __builtin_amdgcn_global_load_lds((__attribute__((address_space(1))) const void*)g,
                                   (__attribute__((address_space(3))) void*)l,
                                   16, 0, 0);
}

// ---------------- convert kernels ----------------
__global__ __launch_bounds__(256) void cvt_x(const float* __restrict__ x,
                                             unsigned short* __restrict__ xb) {
  const size_t i = (size_t)blockIdx.x * 256 + threadIdx.x;
  const float4 v = ((const float4*)x)[i];
  ushort4 o;
  o.x = f2b(v.x); o.y = f2b(v.y); o.z = f2b(v.z); o.w = f2b(v.w);
  ((ushort4*)xb)[i] = o;
}

__global__ __launch_bounds__(256) void prep_weights(
    const float* __restrict__ Wq, const float* __restrict__ Wk,
    const float* __restrict__ Wv, const float* __restrict__ Wp,
    const float* __restrict__ bq, const float* __restrict__ bk,
    const float* __restrict__ bv,
    unsigned short* __restrict__ wqkv, unsigned short* __restrict__ wp,
    float* __restrict__ bias_qkv) {
  const int idx = blockIdx.x * 256 + threadIdx.x;
  if (idx < 786432) {                       // 1536*512
    const int m = idx >> 9, i = idx & 511;
    const float* W = (m < 512) ? Wq : ((m < 1024) ? Wk : Wv);
    wqkv[idx] = f2b(W[(m & 511) * 512 + i]);
    return;
  }
  const int j = idx - 786432;
  if (j < 262144) { wp[j] = f2b(Wp[j]); return; }
  const int c = j - 262144;
  if (c < 1536)
    bias_qkv[c] = (c < 512) ? bq[c] : ((c < 1024) ? bk[c - 512] : bv[c - 1024]);
}

// ---------------- m97-style bf16 GEMM, B^T input, XCD-swizzled ----------------
// SOFT=1: fused per-head softmax on q/k regions, coalesced bf16 store via LDS repack.
// SOFT=0: plain fp32 store + bias.
template<int SOFT>
__global__ __launch_bounds__(256, 2) void gemm_bt(
    const unsigned short* __restrict__ A,
    const unsigned short* __restrict__ Bm,
    const float* __restrict__ bias,
    void* __restrict__ C,
    int M, int N, int K, int ldc)
{
  __shared__ unsigned short sh[2 * 128 * 32];
  unsigned short* As = sh;
  unsigned short* Bs = sh + 128 * 32;
  const int tid  = threadIdx.x;
  const int wave = tid >> 6;
  const int lane = tid & 63;
  const int quad = lane >> 4;
  const int lr   = lane & 15;
  // XCD swizzle: keep all n-tiles of an m-tile on one XCD (L2 A-reuse)
  const int bid  = ((blockIdx.x & 7) * (gridDim.x >> 3)) + (blockIdx.x >> 3);
  const int nt   = N >> 7;
  const int bn   = (bid % nt) << 7;
  const int bm   = (bid / nt) << 7;
  const int half = wave >> 1;
  const int wm   = half << 6;
  const int wn   = (wave & 1) << 6;

  floatx4 acc[4][4] = {};

  const int srow = tid >> 2;
  const int scol = (tid & 3) << 3;
  const unsigned short* Ag = A + (size_t)(bm + srow) * K + scol;
  const unsigned short* Bg = Bm + (size_t)(bn + srow) * K + scol;
  unsigned short* Al = As + (wave << 9);
  unsigned short* Bl = Bs + (wave << 9);

  for (int k0 = 0; k0 < K; k0 += 32) {
    __syncthreads();
    gl_lds16(Ag + k0, Al);
    gl_lds16(Ag + (size_t)64 * K + k0, Al + 64 * 32);
    gl_lds16(Bg + k0, Bl);
    gl_lds16(Bg + (size_t)64 * K + k0, Bl + 64 * 32);
    __syncthreads();

    frag8 af[4], bf[4];
#pragma unroll
    for (int i = 0; i < 4; i++)
      af[i] = *(const frag8*)&As[(wm + (i << 4) + lr) * 32 + (quad << 3)];
#pragma unroll
    for (int j = 0; j < 4; j++)
      bf[j] = *(const frag8*)&Bs[(wn + (j << 4) + lr) * 32 + (quad << 3)];
#pragma unroll
    for (int i = 0; i < 4; i++)
#pragma unroll
      for (int j = 0; j < 4; j++)
        acc[i][j] = __builtin_amdgcn_mfma_f32_16x16x32_bf16(af[i], bf[j], acc[i][j], 0, 0, 0);
  }

  // epilogue: C/D layout col=lane&15, row=quad*4+reg
  const int ccol0 = bn + wn + lr;

  // bias into acc
#pragma unroll
  for (int j = 0; j < 4; j++) {
    const float bv = bias[ccol0 + (j << 4)];
#pragma unroll
    for (int i = 0; i < 4; i++)
#pragma unroll
      for (int r = 0; r < 4; r++)
        acc[i][j][r] += bv;
  }

  if (SOFT) {
    const int region = (bn + wn) >> 9;   // 0=q, 1=k, 2=v (wave-uniform)
    if (region < 2) {
#pragma unroll
      for (int i = 0; i < 4; i++)
#pragma unroll
        for (int r = 0; r < 4; r++) {
          // softmax over the 64 head-dims: 4 j-vals/lane x 16 lanes (same quad)
          float e0 = __expf(acc[i][0][r]);
          float e1 = __expf(acc[i][1][r]);
          float e2 = __expf(acc[i][2][r]);
          float e3 = __expf(acc[i][3][r]);
          float s = e0 + e1 + e2 + e3;
          s += __shfl_xor(s, 1);
          s += __shfl_xor(s, 2);
          s += __shfl_xor(s, 4);
          s += __shfl_xor(s, 8);
          const float inv = 1.f / s;
          acc[i][0][r] = e0 * inv; acc[i][1][r] = e1 * inv;
          acc[i][2][r] = e2 * inv; acc[i][3][r] = e3 * inv;
        }
    }
    // coalesced bf16 store: repack 64-row halves through the (dead) staging LDS
    unsigned short* os = sh;             // 64 x 128 bf16 = 16 KB
#pragma unroll
    for (int p = 0; p < 2; p++) {
      __syncthreads();
      if (half == p) {
#pragma unroll
        for (int i = 0; i < 4; i++)
#pragma unroll
          for (int j = 0; j < 4; j++)
#pragma unroll
            for (int r = 0; r < 4; r++)
              os[((i << 4) + (quad << 2) + r) * 128 + wn + (j << 4) + lr] = f2b(acc[i][j][r]);
      }
      __syncthreads();
#pragma unroll
      for (int it = 0; it < 4; it++) {
        const int idx = (it << 8) + tid;   // 1024 uint4 total
        const int row = idx >> 4;
        const int c8  = (idx & 15) << 3;
        *(uint4*)((unsigned short*)C + (size_t)(bm + (p << 6) + row) * ldc + bn + c8) =
            *(const uint4*)&os[row * 128 + c8];
      }
    }
  } else {
    const int crow0 = bm + wm + (quad << 2);
#pragma unroll
    for (int j = 0; j < 4; j++) {
      const int col = ccol0 + (j << 4);
#pragma unroll
      for (int i = 0; i < 4; i++) {
        const int row = crow0 + (i << 4);
#pragma unroll
        for (int r = 0; r < 4; r++)
          ((float*)C)[(size_t)(row + r) * ldc + col] = acc[i][j][r];
      }
    }
  }
}

// ---------------- partial ctxT[e][d] + ksum partial per (chunk,bh) ----------------
__global__ __launch_bounds__(256) void kv_context(const unsigned short* __restrict__ qkv,
                                                  float* __restrict__ part,
                                                  float* __restrict__ ksp) {
  const int bid = blockIdx.x;          // 32 bh x 32 t-chunks
  const int tc  = bid & 31;
  const int bh  = bid >> 5;
  const int b   = bh >> 3, h = bh & 7;
  __shared__ float ks[16 * 64];
  __shared__ float vs[16 * 64];
  const int tid = threadIdx.x;
  const int ty = tid >> 4, tx = tid & 15;
  floatx4 acc[4] = {};
  floatx4 ksacc = {0.f, 0.f, 0.f, 0.f};

  const int si    = tid << 3;
  const int strow = si >> 7;
  const int sw    = si & 127;
  const int t0    = b * TT + tc * 128;
  const unsigned short* gcol = qkv + ((sw < 64) ? (512 + h * 64 + sw)
                                                : (1024 + h * 64 + (sw - 64)));
  float* sdst = (sw < 64) ? &ks[strow * 64 + sw] : &vs[strow * 64 + (sw - 64)];

  for (int tt = 0; tt < 128; tt += 16) {
    __syncthreads();
    const uint4 raw = *(const uint4*)(gcol + (size_t)(t0 + tt + strow) * NQKV);
    sdst[0] = blo(raw.x); sdst[1] = bhi(raw.x);
    sdst[2] = blo(raw.y); sdst[3] = bhi(raw.y);
    sdst[4] = blo(raw.z); sdst[5] = bhi(raw.z);
    sdst[6] = blo(raw.w); sdst[7] = bhi(raw.w);
    __syncthreads();
#pragma unroll
    for (int t = 0; t < 16; t++) {
      const floatx4 vb = *(const floatx4*)&vs[t * 64 + (ty << 2)];  // 4 e's
      const floatx4 kb = *(const floatx4*)&ks[t * 64 + (tx << 2)];  // 4 d's
      acc[0] += vb.x * kb;
      acc[1] += vb.y * kb;
      acc[2] += vb.z * kb;
      acc[3] += vb.w * kb;
    }
    // ksum partial: this thread covers t==ty for its 4 d's
    ksacc += *(const floatx4*)&ks[ty * 64 + (tx << 2)];
  }
  // reduce ksacc across ty via LDS (vs is dead)
  __syncthreads();
  *(floatx4*)&vs[ty * 64 + (tx << 2)] = ksacc;
  __syncthreads();

  float* pg = part + ((size_t)(tc * 32 + bh) << 12) + (size_t)(ty << 2) * 64 + (tx << 2);
#pragma unroll
  for (int i = 0; i < 4; i++)
    *(floatx4*)(pg + i * 64) = acc[i];

  if (tid < 64) {
    float s = 0.f;
    for (int t2 = 0; t2 < 16; t2++) s += vs[t2 * 64 + tid];
    ksp[(tc * 32 + bh) * 64 + tid] = s;
  }
}

// ---------------- reduce partials -> ctxb bf16 [bh][80][64] ----------------
// rows 0-63 = ctxT, row 64 = ksum, rows 65-79 = 0
__global__ __launch_bounds__(256) void ctx_reduce(const float* __restrict__ part,
                                                  const float* __restrict__ ksp,
                                                  unsigned short* __restrict__ ctxb) {
  const int bh = blockIdx.x / 20, g = blockIdx.x % 20;   // 20 groups x 4 rows = 80 rows
  const int row = (g << 2) + (threadIdx.x >> 6);
  const int d   = threadIdx.x & 63;
  float s = 0.f;
  if (row < 64) {
    const float* p = part + ((size_t)bh << 12) + row * 64 + d;
    for (int c = 0; c < 32; c++) s += p[(size_t)c << 17];
  } else if (row == 64) {
    const float* p = ksp + bh * 64 + d;
    for (int c = 0; c < 32; c++) s += p[c << 11];
  }
  ctxb[(size_t)bh * 5120 + (row << 6) + d] = f2b(s);
}

// ---------------- attn_out via MFMA: outT[e][t] = ctxT[e][:]·q'[t][:] ----------------
__global__ __launch_bounds__(256) void attn_out(const unsigned short* __restrict__ qkv,
                                                const unsigned short* __restrict__ ctxb,
                                                unsigned short* __restrict__ opre) {
  const int bid = blockIdx.x;          // bh(32) x tchunk(64)
  const int tc = bid & 63;
  const int bh = bid >> 6;
  const int b = bh >> 3, h = bh & 7;
  const int t0 = b * TT + (tc << 6);
  __shared__ unsigned short sh[144 * 72];   // qs[64][72] | cs[80][72] (cs reused as os)
  unsigned short* qs = sh;
  unsigned short* cs = sh + 64 * 72;
  unsigned short* os = cs;
  const int tid = threadIdx.x;

  for (int i = tid; i < 512; i += 256) {
    const int row = i >> 3, c8 = (i & 7) << 3;
    *(uint4*)&qs[row * 72 + c8] =
        *(const uint4*)&qkv[(size_t)(t0 + row) * NQKV + h * 64 + c8];
  }
  for (int i = tid; i < 640; i += 256) {
    const int row = i >> 3, c8 = (i & 7) << 3;
    *(uint4*)&cs[row * 72 + c8] =
        *(const uint4*)&ctxb[(size_t)bh * 5120 + (row << 6) + c8];
  }
  __syncthreads();

  const int lane = tid & 63, w = tid >> 6, quad = lane >> 4, lr = lane & 15;
  floatx4 acc[5] = {};
#pragma unroll
  for (int k2 = 0; k2 < 2; k2++) {
    const int d0 = (k2 << 5) + (quad << 3);
    const frag8 bf = *(const frag8*)&qs[((w << 4) + lr) * 72 + d0];
#pragma unroll
    for (int et = 0; et < 5; et++) {
      const frag8 af = *(const frag8*)&cs[(et * 16 + lr) * 72 + d0];
      acc[et] = __builtin_amdgcn_mfma_f32_16x16x32_bf16(af, bf, acc[et], 0, 0, 0);
    }
  }
  const float dinv = 1.f / __shfl(acc[4][0], lr);
  __syncthreads();                      // done reading cs; reuse as os

  const int trow = (w << 4) + lr;
#pragma unroll
  for (int et = 0; et < 4; et++)
#pragma unroll
    for (int r = 0; r < 4; r++) {
      const int e = et * 16 + (quad << 2) + r;
      const float qv = b2f(qs[trow * 72 + e]);
      os[trow * 72 + e] = f2b(acc[et][r] * dinv + qv);
    }
  __syncthreads();

  for (int i = tid; i < 512; i += 256) {
    const int row = i >> 3, c8 = (i & 7) << 3;
    *(uint4*)&opre[(size_t)(t0 + row) * KDIM + h * 64 + c8] = *(const uint4*)&os[row * 72 + c8];
  }
}

// ---------------- launch ----------------
extern "C" void kernel_launch(void* const* d_in, const int* in_sizes, int n_in,
                              void* d_out, int out_size, void* d_ws, size_t ws_size,
                              hipStream_t stream) {
  (void)in_sizes; (void)n_in; (void)out_size; (void)ws_size;
  const float* x  = (const float*)d_in[0];
  const float* Wq = (const float*)d_in[1];
  const float* bq = (const float*)d_in[2];
  const float* Wk = (const float*)d_in[3];
  const float* bk = (const float*)d_in[4];
  const float* Wv = (const float*)d_in[5];
  const float* bv = (const float*)d_in[6];
  const float* Wp = (const float*)d_in[7];
  const float* bp = (const float*)d_in[8];

  char* w = (char*)d_ws;
  unsigned short* xb   = (unsigned short*)w; w += (size_t)NTOK * KDIM * 2;   // 16 MB
  float* part          = (float*)xb;         // alias: xb dead after qkv GEMM; 1024*4096*4 = 16 MB
  unsigned short* wqkv = (unsigned short*)w; w += (size_t)NQKV * KDIM * 2;   // 1.5 MB
  unsigned short* wp   = (unsigned short*)w; w += (size_t)KDIM * KDIM * 2;   // 0.5 MB
  float* bias_qkv      = (float*)w;          w += (size_t)NQKV * 4;          // 6 KB
  float* ksp           = (float*)w;          w += (size_t)1024 * 64 * 4;     // 256 KB
  unsigned short* ctxb = (unsigned short*)w; w += (size_t)32 * 80 * 64 * 2;  // 320 KB
  unsigned short* qkv  = (unsigned short*)w; w += (size_t)NTOK * NQKV * 2;   // 48 MB
  unsigned short* opre = (unsigned short*)w; w += (size_t)NTOK * KDIM * 2;   // 16 MB

  cvt_x<<<8192, 256, 0, stream>>>(x, xb);
  prep_weights<<<4102, 256, 0, stream>>>(Wq, Wk, Wv, Wp, bq, bk, bv, wqkv, wp, bias_qkv);
  gemm_bt<1><<<(NTOK / 128) * (NQKV / 128), 256, 0, stream>>>(
      xb, wqkv, bias_qkv, qkv, NTOK, NQKV, KDIM, NQKV);
  kv_context<<<1024, 256, 0, stream>>>(qkv, part, ksp);
  ctx_reduce<<<640, 256, 0, stream>>>(part, ksp, ctxb);
  attn_out<<<2048, 256, 0, stream>>>(qkv, ctxb, opre);
  gemm_bt<0><<<(NTOK / 128) * (KDIM / 128), 256, 0, stream>>>(
      opre, wp, bp, d_out, NTOK, KDIM, KDIM, KDIM);
}